// Round 2
// baseline (352.272 us; speedup 1.0000x reference)
//
#include <hip/hip_runtime.h>
#include <math.h>

// Fused morphological opening: erode(10x10 flat, SAME) then dilate(10x10 flat,
// SAME), NHWC fp32 [16,512,512,8]. One kernel; eroded intermediate lives in LDS.
//
// R1 -> R2 change: XOR bank swizzle on the LDS f4 index.
//   idx(r,c) = r*S_A + (c ^ (r&7)),  S_A = 104 f4 (multiple of 8).
// R1 evidence: SQ_LDS_BANK_CONFLICT = 2.6e7 cycles/dispatch (~42 us/CU) from
// the row-strided b128 reads/writes in the horizontal passes (stride 101 f4 ==
// 20 mod 32 banks -> 4-8 way collisions). With stride % 8 == 0 the bank slot
// is purely (c ^ (r&7)) % 8: row-strided access spreads over all 8 slots,
// column-consecutive access is permuted within aligned 8-groups (still free).
// S_A=104 forces RA=39 rows (64,896 B <= 64 KB static LDS) -> TH=30.
//
// Decomposition per 30x32-px output tile (single LDS buffer, in-place passes
// via read-stage -> barrier -> write):
//   P1 minV : global -> sA   39 rows (h0-4..h0+34) x 100 f4 (px w0-8..w0+41)
//   P2 minH : sA -> sA       39 rows x 82 f4   (eroded px w0-4..w0+36)
//   P3 maxV : sA -> sA       30 rows x 82 f4   (abs-row mask = -inf pad)
//   P4 maxH : sA -> sA       30 rows x 64 f4   (abs-px  mask = -inf pad)
//   P5 copy : sA -> global   coalesced, 1 KB per wave-store
// All passes: Gil-Werman run-of-8 (17 taps -> 8 outputs).
// Boundary semantics (lax.reduce_window SAME): erosion pads input +inf;
// dilation pads the *eroded image* -inf outside [0,512) (abs masks in P3/P4).
// LDS = 39*104*16 = 64,896 B -> 2 blocks/CU, 16 waves/CU (50% cap).

#define W_F4   1024              // 512 px * 2 f4 (8 ch)
#define IMG_F4 (512 * W_F4)
#define TH     30                // output rows per tile
#define TW     32                // output px per tile
#define RA     39                // sA rows = TH + 9
#define CA     100               // minV cols (f4) = (TW + 18) * 2
#define S_A    104               // sA row stride (f4), multiple of 8
#define CB     82                // eroded cols (f4) = (TW + 9) * 2
#define NJ     41                // eroded px per row = TW + 9

__device__ __forceinline__ int sw(int r, int c) {   // bank-swizzled f4 index
    return r * S_A + (c ^ (r & 7));                 // c <= 99 -> c^7 <= 103 < S_A
}

__device__ __forceinline__ float4 f4min(float4 a, float4 b) {
    return make_float4(fminf(a.x,b.x), fminf(a.y,b.y), fminf(a.z,b.z), fminf(a.w,b.w));
}
__device__ __forceinline__ float4 f4max(float4 a, float4 b) {
    return make_float4(fmaxf(a.x,b.x), fmaxf(a.y,b.y), fmaxf(a.z,b.z), fmaxf(a.w,b.w));
}

__global__ __launch_bounds__(512, 4) void opening(const float4* __restrict__ in,
                                                  float4* __restrict__ out) {
    __shared__ float4 sA[RA * S_A];          // 64,896 B

    const float4 pinf4 = make_float4( INFINITY,  INFINITY,  INFINITY,  INFINITY);
    const float4 ninf4 = make_float4(-INFINITY, -INFINITY, -INFINITY, -INFINITY);

    const int t  = threadIdx.x;
    const int h0 = blockIdx.y * TH;          // last band ragged (h0 = 510)
    const int w0 = blockIdx.x * TW;

    const float4* img  = in  + (size_t)blockIdx.z * IMG_F4;
    float4*       oimg = out + (size_t)blockIdx.z * IMG_F4;

    // ---- P1: vertical min, global -> sA. 500 tasks: c in [0,100), run p in [0,5) ----
    // sA row s <-> abs row h0-4+s. 17 upfront global loads per task (latency ILP).
    if (t < 5 * CA) {
        const int c = t % CA;                // lanes = consecutive f4 cols (coalesced)
        const int p = t / CA;
        const int colf4 = w0 * 2 - 16 + c;
        const bool colok = (colf4 >= 0) & (colf4 < W_F4);

        float4 v[17];
#pragma unroll
        for (int q = 0; q < 17; q++) {       // input abs rows (h0-8) + p*8 + q
            int h = h0 + p * 8 + q - 8;
            bool ok = colok & (h >= 0) & (h < 512);
            v[q] = ok ? img[(size_t)h * W_F4 + colf4] : pinf4;
        }
        float4 L[9]; L[8] = v[8];
#pragma unroll
        for (int i = 7; i >= 0; i--) L[i] = f4min(v[i], L[i + 1]);
        float4 rr = v[9];
#pragma unroll
        for (int i = 0; i < 8; i++) {
            if (i > 0) rr = f4min(rr, v[9 + i]);
            int s = p * 8 + i;
            if (s < RA) sA[sw(s, c)] = f4min(L[i], rr);   // rows 0..38 (skip s=39)
        }
    }
    __syncthreads();

    // ---- P2: horizontal min, sA -> sA in place. 468 tasks: c4 x 39 rows x 6 runs ----
    {
        const bool act = t < 2 * RA * 6;
        int r = 0, c4 = 0, j0 = 0;
        float4 o8[8];
        if (act) {
            c4 = t & 1;
            r  = (t >> 1) % RA;
            j0 = ((t >> 1) / RA) * 8;        // output px j = j0+i, valid j < 41
            // prefix L over taps j0..j0+8 (k <= 48, c <= 97: always in range)
            float4 L[9]; L[8] = sA[sw(r, 2 * (j0 + 8) + c4)];
#pragma unroll
            for (int i = 7; i >= 0; i--) L[i] = f4min(sA[sw(r, 2 * (j0 + i) + c4)], L[i + 1]);
            float4 rr;
#pragma unroll
            for (int i = 0; i < 8; i++) {    // suffix taps j0+9+i, guard k < 50
                int k = j0 + 9 + i;
                float4 tap = (k < 50) ? sA[sw(r, 2 * k + c4)] : pinf4;
                rr = i ? f4min(rr, tap) : tap;
                o8[i] = f4min(L[i], rr);
            }
        }
        __syncthreads();                     // all P2 reads done before any write
        if (act) {
#pragma unroll
            for (int i = 0; i < 8; i++) {
                int j = j0 + i;
                if (j < NJ) sA[sw(r, 2 * j + c4)] = o8[i];
            }
        }
    }
    __syncthreads();

    // ---- P3: vertical max, sA -> sA rows [0,30). 328 tasks: c in [0,82) x 4 runs ----
    // Tap valid iff eroded abs row h0-4+s in [0,512) (else -inf = dilation SAME pad).
    {
        const bool act = t < CB * 4;
        int c = 0, o0 = 0;
        float4 o8[8];
        if (act) {
            c  = t % CB;                     // lanes = consecutive f4 (conflict-free)
            o0 = (t / CB) * 8;               // output rows o0+i, valid o < 30
            float4 L[9];
#pragma unroll
            for (int i = 8; i >= 0; i--) {   // taps s = o0..o0+8 <= 32 (in range)
                int s = o0 + i;
                int h = h0 - 4 + s;
                float4 tap = ((h >= 0) & (h < 512)) ? sA[sw(s, c)] : ninf4;
                L[i] = (i == 8) ? tap : f4max(tap, L[i + 1]);
            }
            float4 rr;
#pragma unroll
            for (int i = 0; i < 8; i++) {    // taps s = o0+9+i, s=39/40 -> out of buf
                int s = o0 + 9 + i;
                int h = h0 - 4 + s;
                float4 tap = ((s < RA) & (h >= 0) & (h < 512)) ? sA[sw(s, c)] : ninf4;
                rr = i ? f4max(rr, tap) : tap;
                o8[i] = f4max(L[i], rr);
            }
        }
        __syncthreads();
        if (act) {
#pragma unroll
            for (int i = 0; i < 8; i++) {
                int o = o0 + i;
                if (o < TH) sA[sw(o, c)] = o8[i];
            }
        }
    }
    __syncthreads();

    // ---- P4: horizontal max, sA -> sA cols [0,64). 240 tasks: c4 x 30 rows x 4 runs ----
    // Tap valid iff eroded abs px w0-4+j in [0,512) (else -inf).
    {
        const bool act = t < 2 * TH * 4;
        int r = 0, c4 = 0, x0 = 0;
        float4 o8[8];
        if (act) {
            c4 = t & 1;
            r  = (t >> 1) % TH;
            x0 = ((t >> 1) / TH) * 8;        // output px x0+i, 4*8 = 32 exact
            float4 L[9];
#pragma unroll
            for (int i = 8; i >= 0; i--) {   // taps j = x0..x0+8 <= 32 (in range)
                int j = x0 + i;
                int px = w0 - 4 + j;
                float4 tap = ((px >= 0) & (px < 512)) ? sA[sw(r, 2 * j + c4)] : ninf4;
                L[i] = (i == 8) ? tap : f4max(tap, L[i + 1]);
            }
            float4 rr;
#pragma unroll
            for (int i = 0; i < 8; i++) {    // taps j = x0+9+i <= 40 (in range)
                int j = x0 + 9 + i;
                int px = w0 - 4 + j;
                float4 tap = ((px >= 0) & (px < 512)) ? sA[sw(r, 2 * j + c4)] : ninf4;
                rr = i ? f4max(rr, tap) : tap;
                o8[i] = f4max(L[i], rr);
            }
        }
        __syncthreads();
        if (act) {
#pragma unroll
            for (int i = 0; i < 8; i++)
                sA[sw(r, 2 * (x0 + i) + c4)] = o8[i];
        }
    }
    __syncthreads();

    // ---- P5: coalesced copy sA -> global (lanes = consecutive f4, 1 KB/wave) ----
    for (int idx = t; idx < TH * 64; idx += 512) {
        int r = idx >> 6;
        int c = idx & 63;
        int h = h0 + r;
        if (h < 512)
            oimg[(size_t)h * W_F4 + (size_t)(w0 * 2 + c)] = sA[sw(r, c)];
    }
}

extern "C" void kernel_launch(void* const* d_in, const int* in_sizes, int n_in,
                              void* d_out, int out_size, void* d_ws, size_t ws_size,
                              hipStream_t stream) {
    const float4* in  = (const float4*)d_in[0];
    float4*       out = (float4*)d_out;
    (void)d_ws; (void)ws_size;               // workspace not needed

    dim3 grid(512 / TW, (512 + TH - 1) / TH, 16);   // 16 x 18 x 16 = 4608 blocks
    opening<<<grid, 512, 0, stream>>>(in, out);
}

// Round 3
// 328.512 us; speedup vs baseline: 1.0723x; 1.0723x over previous
//
#include <hip/hip_runtime.h>
#include <math.h>

// Fused morphological opening: erode(10x10 flat, SAME) then dilate(10x10 flat,
// SAME), NHWC fp32 [16,512,512,8]. One kernel; eroded intermediate lives in LDS.
//
// R2 -> R3: REVERT the XOR bank swizzle (R2 evidence: conflicts 26M->9.6M yet
// dur 162->198 us. Bank math: stride 101 f4 = 404 dw = 20 mod 32 banks spreads
// b128 starts uniformly over all 8 aligned 4-bank groups -> the counted
// "conflicts" are the 1024B/8cy throughput floor, not lost cycles. The swizzle
// only added per-tap XOR address math + broke offset folding.)
// R3 change: tile 30x32 -> 23x32 so LDS = 32*101*16 = 51,712 B -> 3 blocks/CU
// (24 waves, 75% occupancy cap, was 2 blocks/50%). R1 counters showed nothing
// saturated (HBM 18%, VALU 33%, LDS pipe ~20%) with occupancy 43% -> latency-
// bound on the 7-barrier per-block chain; more co-resident blocks is the fix.
//
// Decomposition per 23x32-px output tile (single LDS buffer, in-place passes
// via read-stage -> barrier -> write):
//   P1 minV : global -> sA   32 rows (h0-4..h0+27) x 100 f4 (px w0-8..w0+41)
//   P2 minH : sA -> sA       32 rows x 82 f4   (eroded px w0-4..w0+36)
//   P3 maxV : sA -> sA       23 rows x 82 f4   (abs-row mask = -inf pad)
//   P4 maxH : sA -> sA       23 rows x 64 f4   (abs-px  mask = -inf pad)
//   P5 copy : sA -> global   coalesced, 1 KB per wave-store
// All passes: Gil-Werman run-of-8 (17 taps -> 8 outputs).
// Boundary semantics (lax.reduce_window SAME): erosion pads input +inf;
// dilation pads the *eroded image* -inf outside [0,512) (abs masks in P3/P4).

#define W_F4   1024              // 512 px * 2 f4 (8 ch)
#define IMG_F4 (512 * W_F4)
#define TH     23                // output rows per tile
#define TW     32                // output px per tile
#define RA     32                // sA rows = TH + 9 (4 runs of 8, exact)
#define CA     100               // minV cols (f4) = (TW + 18) * 2
#define S_A    101               // sA row stride (f4), odd (uniform bank spread)
#define CB     82                // eroded cols (f4) = (TW + 9) * 2
#define NJ     41                // eroded px per row = TW + 9

__device__ __forceinline__ float4 f4min(float4 a, float4 b) {
    return make_float4(fminf(a.x,b.x), fminf(a.y,b.y), fminf(a.z,b.z), fminf(a.w,b.w));
}
__device__ __forceinline__ float4 f4max(float4 a, float4 b) {
    return make_float4(fmaxf(a.x,b.x), fmaxf(a.y,b.y), fmaxf(a.z,b.z), fmaxf(a.w,b.w));
}

__global__ __launch_bounds__(512, 6) void opening(const float4* __restrict__ in,
                                                  float4* __restrict__ out) {
    __shared__ float4 sA[RA * S_A];          // 51,712 B -> 3 blocks/CU

    const float4 pinf4 = make_float4( INFINITY,  INFINITY,  INFINITY,  INFINITY);
    const float4 ninf4 = make_float4(-INFINITY, -INFINITY, -INFINITY, -INFINITY);

    const int t  = threadIdx.x;
    const int h0 = blockIdx.y * TH;          // last band ragged (h0 = 506)
    const int w0 = blockIdx.x * TW;

    const float4* img  = in  + (size_t)blockIdx.z * IMG_F4;
    float4*       oimg = out + (size_t)blockIdx.z * IMG_F4;

    // ---- P1: vertical min, global -> sA. 400 tasks: c in [0,100), run p in [0,4) ----
    // sA row s <-> eroded abs row h0-4+s. 17 upfront global loads (latency ILP).
    if (t < 4 * CA) {
        const int c = t % CA;                // lanes = consecutive f4 cols (coalesced)
        const int p = t / CA;
        const int colf4 = w0 * 2 - 16 + c;
        const bool colok = (colf4 >= 0) & (colf4 < W_F4);

        float4 v[17];
#pragma unroll
        for (int q = 0; q < 17; q++) {       // input abs rows (h0-8) + p*8 + q
            int h = h0 + p * 8 + q - 8;
            bool ok = colok & (h >= 0) & (h < 512);
            v[q] = ok ? img[(size_t)h * W_F4 + colf4] : pinf4;
        }
        float4 L[9]; L[8] = v[8];
#pragma unroll
        for (int i = 7; i >= 0; i--) L[i] = f4min(v[i], L[i + 1]);
        float4 rr = v[9];
#pragma unroll
        for (int i = 0; i < 8; i++) {
            if (i > 0) rr = f4min(rr, v[9 + i]);
            sA[(p * 8 + i) * S_A + c] = f4min(L[i], rr);   // 4*8 = 32 rows exact
        }
    }
    __syncthreads();

    // ---- P2: horizontal min, sA -> sA in place. 384 tasks: c4 x 32 rows x 6 runs ----
    {
        const bool act = t < 2 * RA * 6;
        int base = 0, j0 = 0;
        float4 o8[8];
        if (act) {
            const int c4 = t & 1;
            const int r  = (t >> 1) & (RA - 1);   // RA = 32, power of two
            j0 = ((t >> 1) >> 5) * 8;        // output px j = j0+i, valid j < 41
            base = r * S_A + c4;
            // prefix L over taps j0..j0+8 (k <= 48, col 2k+c4 <= 97: in range)
            float4 L[9]; L[8] = sA[base + 2 * (j0 + 8)];
#pragma unroll
            for (int i = 7; i >= 0; i--) L[i] = f4min(sA[base + 2 * (j0 + i)], L[i + 1]);
            float4 rr;
#pragma unroll
            for (int i = 0; i < 8; i++) {    // suffix taps j0+9+i, guard k < 50
                int k = j0 + 9 + i;
                float4 tap = (k < 50) ? sA[base + 2 * k] : pinf4;
                rr = i ? f4min(rr, tap) : tap;
                o8[i] = f4min(L[i], rr);
            }
        }
        __syncthreads();                     // all P2 reads done before any write
        if (act) {
#pragma unroll
            for (int i = 0; i < 8; i++) {
                int j = j0 + i;
                if (j < NJ) sA[base + 2 * j] = o8[i];
            }
        }
    }
    __syncthreads();

    // ---- P3: vertical max, sA -> sA rows [0,23). 246 tasks: c in [0,82) x 3 runs ----
    // Tap valid iff eroded abs row h0-4+s in [0,512) (else -inf = dilation SAME pad).
    {
        const bool act = t < CB * 3;
        int c = 0, o0 = 0;
        float4 o8[8];
        if (act) {
            c  = t % CB;                     // lanes = consecutive f4 (uniform banks)
            o0 = (t / CB) * 8;               // output rows o0+i, valid o < 23
            float4 L[9];
#pragma unroll
            for (int i = 8; i >= 0; i--) {   // taps s = o0..o0+8 <= 24 (in range)
                int s = o0 + i;
                int h = h0 - 4 + s;
                float4 tap = ((h >= 0) & (h < 512)) ? sA[s * S_A + c] : ninf4;
                L[i] = (i == 8) ? tap : f4max(tap, L[i + 1]);
            }
            float4 rr;
#pragma unroll
            for (int i = 0; i < 8; i++) {    // taps s = o0+9+i <= 32 -> guard s < RA
                int s = o0 + 9 + i;
                int h = h0 - 4 + s;
                float4 tap = ((s < RA) & (h >= 0) & (h < 512)) ? sA[s * S_A + c] : ninf4;
                rr = i ? f4max(rr, tap) : tap;
                o8[i] = f4max(L[i], rr);
            }
        }
        __syncthreads();
        if (act) {
#pragma unroll
            for (int i = 0; i < 8; i++) {
                int o = o0 + i;
                if (o < TH) sA[o * S_A + c] = o8[i];
            }
        }
    }
    __syncthreads();

    // ---- P4: horizontal max, sA -> sA cols [0,64). 184 tasks: c4 x 23 rows x 4 runs ----
    // Tap valid iff eroded abs px w0-4+j in [0,512) (else -inf).
    {
        const bool act = t < 2 * TH * 4;
        int base = 0, x0 = 0;
        float4 o8[8];
        if (act) {
            const int c4 = t & 1;
            const int r  = (t >> 1) % TH;
            x0 = ((t >> 1) / TH) * 8;        // output px x0+i, 4*8 = 32 exact
            base = r * S_A + c4;
            float4 L[9];
#pragma unroll
            for (int i = 8; i >= 0; i--) {   // taps j = x0..x0+8 <= 32 (in range)
                int j = x0 + i;
                int px = w0 - 4 + j;
                float4 tap = ((px >= 0) & (px < 512)) ? sA[base + 2 * j] : ninf4;
                L[i] = (i == 8) ? tap : f4max(tap, L[i + 1]);
            }
            float4 rr;
#pragma unroll
            for (int i = 0; i < 8; i++) {    // taps j = x0+9+i <= 40 < 41 (in range)
                int j = x0 + 9 + i;
                int px = w0 - 4 + j;
                float4 tap = ((px >= 0) & (px < 512)) ? sA[base + 2 * j] : ninf4;
                rr = i ? f4max(rr, tap) : tap;
                o8[i] = f4max(L[i], rr);
            }
        }
        __syncthreads();
        if (act) {
#pragma unroll
            for (int i = 0; i < 8; i++)
                sA[base + 2 * (x0 + i)] = o8[i];
        }
    }
    __syncthreads();

    // ---- P5: coalesced copy sA -> global (lanes = consecutive f4, 1 KB/wave) ----
    for (int idx = t; idx < TH * 64; idx += 512) {
        int r = idx >> 6;
        int c = idx & 63;
        int h = h0 + r;
        if (h < 512)
            oimg[(size_t)h * W_F4 + (size_t)(w0 * 2 + c)] = sA[r * S_A + c];
    }
}

extern "C" void kernel_launch(void* const* d_in, const int* in_sizes, int n_in,
                              void* d_out, int out_size, void* d_ws, size_t ws_size,
                              hipStream_t stream) {
    const float4* in  = (const float4*)d_in[0];
    float4*       out = (float4*)d_out;
    (void)d_ws; (void)ws_size;               // workspace not needed

    dim3 grid(512 / TW, (512 + TH - 1) / TH, 16);   // 16 x 23 x 16 = 5888 blocks
    opening<<<grid, 512, 0, stream>>>(in, out);
}

// Round 4
// 255.830 us; speedup vs baseline: 1.3770x; 1.2841x over previous
//
#include <hip/hip_runtime.h>
#include <math.h>

// Fused morphological opening: erode(10x10 flat, SAME) then dilate(10x10 flat,
// SAME), NHWC fp32 [16,512,512,8]. One kernel; eroded intermediate in LDS.
//
// R3 post-mortem: occupancy 43->60% made it WORSE (162->176us) -> bottleneck is
// per-CU shared (LDS pipe ~43% incl. 4.8K conflict-cyc/block + VALU instr
// bloat), not wave count. R4 attacks work-per-block, back at TH=31 geometry:
//  (a) Gil-Werman runs of 16 (25 taps -> 16 outputs, two chained 8-chunks):
//      same min-op count, taps/output 2.125 -> 1.56 => ~27% fewer LDS reads
//      (P2/P3/P4), ~21% fewer global loads (P1), ~half the tasks (half the
//      per-task addr/bounds overhead).
//  (b) Interior fast paths: bx in [1,14] & by in [1,15] (77% of blocks) need
//      ZERO bounds checks (new run lengths exactly fit the staged halo).
//      Wave-uniform runtime branch; rim blocks keep per-tap masks.
// Phases (single LDS buffer, in-place via read-stage -> barrier -> write):
//   P1 minV : global -> sA   40 rows x 100 f4, runs {16,16,8}
//   P2 minH : sA -> sA       40 rows x 41 px,  runs {14,14,13} (taps fit 50px)
//   P3 maxV : sA -> sA       31 rows x 82 f4,  runs {16,15}
//   P4 maxH : sA -> sA       31 rows x 32 px,  runs {16,16}
//   P5 copy : sA -> global   coalesced 1KB/wave
// Pad-writes: runs write full 16 (u-tail lands in row-pad col 82..83 / unused
// row 31) - in-bounds scratch, never read. Boundary semantics: erosion pads
// input +inf (P1 stages pinf for OOB cols/rows); dilation pads the *eroded*
// image -inf outside [0,512) (masks in P3/P4 checked paths only).
// LDS = 40*101*16 = 64,640 B -> 2 blocks/CU; launch_bounds(512,4) pins
// VGPR <= 128 so VGPR never drops us below 2 blocks.

#define W_F4   1024              // 512 px * 2 f4 (8 ch)
#define IMG_F4 (512 * W_F4)
#define TH     31                // output rows per tile
#define TW     32                // output px per tile
#define RA     40                // sA rows = TH + 9
#define CA     100               // minV cols (f4) = (TW + 18) * 2
#define S_A    101               // sA row stride (f4)
#define NJ     41                // eroded px per row = TW + 9

__device__ __forceinline__ float4 f4min(float4 a, float4 b) {
    return make_float4(fminf(a.x,b.x), fminf(a.y,b.y), fminf(a.z,b.z), fminf(a.w,b.w));
}
__device__ __forceinline__ float4 f4max(float4 a, float4 b) {
    return make_float4(fmaxf(a.x,b.x), fmaxf(a.y,b.y), fmaxf(a.z,b.z), fmaxf(a.w,b.w));
}
template<bool MIN>
__device__ __forceinline__ float4 f4op(float4 a, float4 b) {
    return MIN ? f4min(a, b) : f4max(a, b);
}

// Gil-Werman run: o[i] = reduce(tap(i) .. tap(i+9)) for i in [0,R), 8<=R<=16.
// Two chained chunks: chunk1 (outs 0..7) prefix L over taps 0..8 + running
// suffix over taps 9..16; chunk2 (outs 8..R-1) prefix L2 over taps 8..16 +
// running suffix over taps 17..R+8. tap(q) must be valid for q in [0,R+9).
template<int R, bool MIN, class F>
__device__ __forceinline__ void gw_run(F tap, float4* o) {
    float4 v8, L[9];
    {
        float4 v[9];
#pragma unroll
        for (int q = 0; q < 9; q++) v[q] = tap(q);
        v8 = v[8];
        L[8] = v[8];
#pragma unroll
        for (int i = 7; i >= 0; i--) L[i] = f4op<MIN>(v[i], L[i + 1]);
    }
    float4 w[8], rr;
#pragma unroll
    for (int i = 0; i < 8; i++) {            // taps 9..16
        float4 tv = tap(9 + i);
        w[i] = tv;
        rr = i ? f4op<MIN>(rr, tv) : tv;
        o[i] = f4op<MIN>(L[i], rr);
    }
    if (R > 8) {
        float4 L2[9];
        L2[8] = w[7];                        // tap 16
#pragma unroll
        for (int i = 7; i >= 1; i--) L2[i] = f4op<MIN>(w[i - 1], L2[i + 1]);
        L2[0] = f4op<MIN>(v8, L2[1]);
        float4 r2;
#pragma unroll
        for (int i = 0; i < R - 8; i++) {    // taps 17..R+8
            float4 tv = tap(17 + i);
            r2 = i ? f4op<MIN>(r2, tv) : tv;
            o[8 + i] = f4op<MIN>(L2[i], r2);
        }
    }
}

__global__ __launch_bounds__(512, 4) void opening(const float4* __restrict__ in,
                                                  float4* __restrict__ out) {
    __shared__ float4 sA[RA * S_A];          // 64,640 B

    const float4 pinf4 = make_float4( INFINITY,  INFINITY,  INFINITY,  INFINITY);
    const float4 ninf4 = make_float4(-INFINITY, -INFINITY, -INFINITY, -INFINITY);

    const int t  = threadIdx.x;
    const int h0 = blockIdx.y * TH;          // last band ragged (h0 = 496)
    const int w0 = blockIdx.x * TW;
    const bool yin = (h0 >= 8) && (h0 + RA < 512);        // by in [1,15]
    const bool xin = (w0 >= 8) && (2 * w0 + 83 < W_F4);   // bx in [1,14]

    const float4* img  = in  + (size_t)blockIdx.z * IMG_F4;
    float4*       oimg = out + (size_t)blockIdx.z * IMG_F4;

    // ---- P1: vertical min, global -> sA. tasks (c in [0,100)) x runs {16,16,8} ----
    // sA row s <-> eroded abs row h0-4+s; taps for s: input rows h0-8+s..h0+1+s.
    if (t < 3 * 128) {
        const int p  = t >> 7;               // wave-uniform run id
        const int id = t & 127;
        if (id < CA) {
            const int s0    = p * 16;
            const int hbase = h0 - 8 + s0;
            const int colf4 = w0 * 2 - 16 + id;
            float4 o[16];
            if (yin) {
                const bool colok = (colf4 >= 0) & (colf4 < W_F4);  // xin -> true
                if (colok) {
                    auto tap = [&](int q) { return img[(size_t)(hbase + q) * W_F4 + colf4]; };
                    if (p < 2) {
                        gw_run<16, true>(tap, o);
#pragma unroll
                        for (int i = 0; i < 16; i++) sA[(s0 + i) * S_A + id] = o[i];
                    } else {
                        gw_run<8, true>(tap, o);
#pragma unroll
                        for (int i = 0; i < 8; i++) sA[(s0 + i) * S_A + id] = o[i];
                    }
                } else {                     // whole column OOB -> +inf
                    const int Rn = (p < 2) ? 16 : 8;
                    for (int i = 0; i < Rn; i++) sA[(s0 + i) * S_A + id] = pinf4;
                }
            } else {                         // rim: per-tap mask (exec-masked load)
                auto tap = [&](int q) {
                    int h = hbase + q;
                    bool ok = (colf4 >= 0) & (colf4 < W_F4) & (h >= 0) & (h < 512);
                    return ok ? img[(size_t)h * W_F4 + colf4] : pinf4;
                };
                if (p < 2) {
                    gw_run<16, true>(tap, o);
#pragma unroll
                    for (int i = 0; i < 16; i++) sA[(s0 + i) * S_A + id] = o[i];
                } else {
                    gw_run<8, true>(tap, o);
#pragma unroll
                    for (int i = 0; i < 8; i++) sA[(s0 + i) * S_A + id] = o[i];
                }
            }
        }
    }
    __syncthreads();

    // ---- P2: horizontal min, sA -> sA in place. (c4 x 40 rows) x runs {14,14,13} ----
    // out j in [0,41): eroded px w0-4+j; taps minV px j..j+9 (staged 50 px).
    // No masks ever: P1 staged +inf for OOB columns. Max tap col u=2: 2*49+1=99.
    {
        const int u  = t >> 7;               // wave-uniform
        const int id = t & 127;
        const bool act = (t < 3 * 128) && (id < 2 * RA);
        int base = 0, j0 = 0;
        float4 o[14];
        if (act) {
            base = (id >> 1) * S_A + (id & 1);
            j0 = u * 14;                     // 0,14,28
            auto tap = [&](int q) { return sA[base + 2 * (j0 + q)]; };
            if (u < 2) gw_run<14, true>(tap, o);
            else       gw_run<13, true>(tap, o);
        }
        __syncthreads();                     // all reads done before any write
        if (act) {
#pragma unroll
            for (int i = 0; i < 14; i++)     // u=2 i=13 -> col 82/83 = row pad (ok)
                sA[base + 2 * (j0 + i)] = o[i];
        }
    }
    __syncthreads();

    // ---- P3: vertical max, sA -> sA rows [0,31). (c in [0,82)) x runs {16,15} ----
    // out o: abs row h0+o; taps eroded rows s=o..o+9 (s<=39). Tap = -inf when
    // eroded abs row h0-4+s outside [0,512) (dilation pads eroded with -inf).
    {
        const int u  = t >> 7;               // wave-uniform
        const int id = t & 127;
        const bool act = (t < 2 * 128) && (id < 82);
        int c = 0, o0 = 0;
        float4 o[16];
        if (act) {
            c  = id;
            o0 = u * 16;                     // 0,16
            if (yin) {
                auto tap = [&](int q) { return sA[(o0 + q) * S_A + c]; };
                gw_run<16, false>(tap, o);   // u=1 extra out lands in row 31 (unused)
            } else {
                auto tap = [&](int q) {
                    int s = o0 + q;
                    float4 val = sA[s * S_A + c];
                    int h = h0 - 4 + s;
                    return ((h >= 0) & (h < 512)) ? val : ninf4;
                };
                gw_run<16, false>(tap, o);
            }
        }
        __syncthreads();                     // all reads done before any write
        if (act) {
#pragma unroll
            for (int i = 0; i < 16; i++)     // rows o0+i <= 31 (row 31 = scratch)
                sA[(o0 + i) * S_A + c] = o[i];
        }
    }
    __syncthreads();

    // ---- P4: horizontal max, sA -> sA cols [0,64). (c4 x 31 rows) x runs {16,16} ----
    // out x: px w0+x; taps eroded j=x..x+9 (j<=40). Tap = -inf when eroded
    // abs px w0-4+j outside [0,512).
    {
        const int u  = t >> 6;               // wave-uniform
        const int id = t & 63;
        const bool act = (t < 2 * 64) && (id < 2 * TH);
        int base = 0, x0 = 0;
        float4 o[16];
        if (act) {
            base = (id >> 1) * S_A + (id & 1);
            x0 = u * 16;                     // 0,16
            if (xin) {
                auto tap = [&](int q) { return sA[base + 2 * (x0 + q)]; };
                gw_run<16, false>(tap, o);
            } else {
                auto tap = [&](int q) {
                    int j = x0 + q;
                    float4 val = sA[base + 2 * j];
                    int px = w0 - 4 + j;
                    return ((px >= 0) & (px < 512)) ? val : ninf4;
                };
                gw_run<16, false>(tap, o);
            }
        }
        __syncthreads();                     // all reads done before any write
        if (act) {
#pragma unroll
            for (int i = 0; i < 16; i++)     // cols <= 63
                sA[base + 2 * (x0 + i)] = o[i];
        }
    }
    __syncthreads();

    // ---- P5: coalesced copy sA -> global (lanes = consecutive f4, 1 KB/wave) ----
    for (int idx = t; idx < TH * 64; idx += 512) {
        int r = idx >> 6;
        int c = idx & 63;
        int h = h0 + r;
        if (yin || h < 512)
            oimg[(size_t)h * W_F4 + (size_t)(w0 * 2 + c)] = sA[r * S_A + c];
    }
}

extern "C" void kernel_launch(void* const* d_in, const int* in_sizes, int n_in,
                              void* d_out, int out_size, void* d_ws, size_t ws_size,
                              hipStream_t stream) {
    const float4* in  = (const float4*)d_in[0];
    float4*       out = (float4*)d_out;
    (void)d_ws; (void)ws_size;               // workspace not needed

    dim3 grid(512 / TW, (512 + TH - 1) / TH, 16);   // 16 x 17 x 16 = 4352 blocks
    opening<<<grid, 512, 0, stream>>>(in, out);
}